// Round 8
// baseline (390.739 us; speedup 1.0000x reference)
//
#include <hip/hip_runtime.h>
#include <math.h>

#define BZ 512
#define NW 128
#define NR 256
#define DD 256

typedef _Float16 half8 __attribute__((ext_vector_type(8)));
typedef __fp16 fp16x2 __attribute__((ext_vector_type(2)));
typedef __attribute__((ext_vector_type(4))) float f32x4;

#define MFMA16(a, b, c) __builtin_amdgcn_mfma_f32_16x16x32_f16(a, b, c, 0, 0, 0)

// ---- LDS layout (bytes) ----
constexpr int TS       = 40;       // staging row stride (u16), 80 B rows
constexpr int BUFB     = 20480;    // one staging buffer
constexpr int TB_OFF   = 40960;    // TB region: 4 wm-groups x 2 bufs x 32x40 u16
constexpr int TBS      = 40;       // TB row stride (u16)
constexpr int MISC_OFF = 61440;
constexpr int LDS_BYTES = MISC_OFF + 6272;   // 67712

union PK2 { fp16x2 h; unsigned int u; };
__device__ __forceinline__ unsigned int pkh(float a, float b) {
  PK2 c; c.h = __builtin_amdgcn_cvt_pkrtz(a, b);
  return c.u;
}
union U8H { unsigned int u[4]; half8 v; };

__device__ __forceinline__ float wred_sum(float v) {
#pragma unroll
  for (int m = 1; m < 64; m <<= 1) v += __shfl_xor(v, m, 64);
  return v;
}
__device__ __forceinline__ float grp16_max(float v) {
#pragma unroll
  for (int m = 1; m < 16; m <<= 1) v = fmaxf(v, __shfl_xor(v, m, 64));
  return v;
}
__device__ __forceinline__ float grp16_sum(float v) {
#pragma unroll
  for (int m = 1; m < 16; m <<= 1) v += __shfl_xor(v, m, 64);
  return v;
}

__global__ __launch_bounds__(512, 4) void wra_fused(
    const float* __restrict__ region, const float* __restrict__ word,
    const float* __restrict__ wattn, float* __restrict__ partial)
{
  extern __shared__ char smem[];
  float* misc = (float*)(smem + MISC_OFF);
  float* PMX  = (float*)smem;              // ph5 only (staging dead)
  float* PSM  = (float*)(smem + 2048);

  const int b    = blockIdx.x;
  const int tid  = threadIdx.x;
  const int lane = tid & 63;
  const int wv   = tid >> 6;   // 0..7
  const int wm   = wv >> 1;    // 0..3  (row band: 32 rows)
  const int wn   = wv & 1;     // 0..1  (col half)
  const int l15  = lane & 15;
  const int lg   = lane >> 4;  // 0..3

  const float* Rb = region + (size_t)b * NR * DD;
  const float* Wb = word   + (size_t)b * NW * DD;
  const float* Ab = wattn  + (size_t)b * NW;

  float* qa   = misc;         // [128]
  float* qs   = misc + 128;   // [128]
  float* wq   = misc + 256;   // [128]
  float* L1   = misc + 384;   // [128]
  float* L2   = misc + 512;   // [128]
  float* dgA  = misc + 640;   // [128]
  float* scal = misc + 768;   // [16]
  float* SMX  = misc + 800;   // [2][128]
  float* SSM  = misc + 1056;  // [2][128]
  float* NSQ  = misc + 1312;  // [2][128]

  // staging thread maps
  const int r_row = tid >> 1;          // ph1 R: 0..255
  const int r_db  = (tid & 1) * 16;
  const int rt_d  = tid & 255;         // ph3 RT
  const int rt_rc = tid >> 8;          // 0/1
  const int w4row = tid >> 2;          // ph4 W: 0..127
  const int w4db  = (tid & 3) * 8;

  float rx[16], wx1[16], rx3[16], wx4[8];

  auto SBUF = [&](int p) { return (unsigned short*)(smem + p * BUFB); };
  auto TBG  = [&](int buf) { return (unsigned short*)(smem + TB_OFF + wm * 5120 + buf * 2560); };

  auto load_R = [&](int d0) {
    const float* src = Rb + r_row * DD + d0 + r_db;
#pragma unroll
    for (int q = 0; q < 4; q++) *(float4*)&rx[4*q] = *(const float4*)(src + 4*q);
  };
  auto stage_R = [&](int p) {
    U8H h0, h1;
#pragma unroll
    for (int j = 0; j < 4; j++) h0.u[j] = pkh(rx[2*j],   rx[2*j+1]);
#pragma unroll
    for (int j = 0; j < 4; j++) h1.u[j] = pkh(rx[8+2*j], rx[9+2*j]);
    *(half8*)(SBUF(p) + r_row * TS + r_db)     = h0.v;
    *(half8*)(SBUF(p) + r_row * TS + r_db + 8) = h1.v;
  };
  auto load_W1 = [&](int d0) {
    const float* s0 = Wb + (32*wm + l15) * DD + d0 + 8*lg;
    const float* s1 = s0 + 16 * DD;
    *(float4*)&wx1[0]  = *(const float4*)(s0);
    *(float4*)&wx1[4]  = *(const float4*)(s0 + 4);
    *(float4*)&wx1[8]  = *(const float4*)(s1);
    *(float4*)&wx1[12] = *(const float4*)(s1 + 4);
  };
  auto load_RT = [&](int r0) {
#pragma unroll
    for (int g = 0; g < 2; g++) {
      const float* src = Rb + (size_t)(r0 + (rt_rc + 2*g) * 8) * DD + rt_d;
#pragma unroll
      for (int i = 0; i < 8; i++) rx3[8*g + i] = src[i * DD];
    }
  };
  auto stage_RT = [&](int p) {
    U8H h0, h1;
#pragma unroll
    for (int j = 0; j < 4; j++) h0.u[j] = pkh(rx3[2*j],   rx3[2*j+1]);
#pragma unroll
    for (int j = 0; j < 4; j++) h1.u[j] = pkh(rx3[8+2*j], rx3[9+2*j]);
    *(half8*)(SBUF(p) + rt_d * TS + rt_rc * 8)       = h0.v;
    *(half8*)(SBUF(p) + rt_d * TS + (rt_rc + 2) * 8) = h1.v;
  };
  auto load_W4 = [&](int d0) {
    const float* src = Wb + w4row * DD + d0 + w4db;
    *(float4*)&wx4[0] = *(const float4*)(src);
    *(float4*)&wx4[4] = *(const float4*)(src + 4);
  };
  auto stage_W4 = [&](int p) {
    U8H h;
#pragma unroll
    for (int j = 0; j < 4; j++) h.u[j] = pkh(wx4[2*j], wx4[2*j+1]);
    *(half8*)(SBUF(p) + w4row * TS + w4db) = h.v;
  };
  auto cvtW2 = [&](half8* ah, half8* al) {
#pragma unroll
    for (int rt = 0; rt < 2; rt++) {
      U8H H, L;
#pragma unroll
      for (int j = 0; j < 4; j++) H.u[j] = pkh(wx1[8*rt+2*j], wx1[8*rt+2*j+1]);
#pragma unroll
      for (int j = 0; j < 4; j++) {
        float la = wx1[8*rt+2*j]   - (float)H.v[2*j];
        float lb = wx1[8*rt+2*j+1] - (float)H.v[2*j+1];
        L.u[j] = pkh(la, lb);
      }
      ah[rt] = H.v; al[rt] = L.v;
    }
  };

  // cross-wave transpose bounce: C-layout chunk (k-tile T) -> row-major A tile
#define TB_WRITE(SRC, T, BF)                                                        \
  if (wn == ((T) >> 2)) {                                                           \
    unsigned short* TBw = TBG(BF);                                                  \
    _Pragma("unroll")                                                               \
    for (int rt_ = 0; rt_ < 2; rt_++) {                                             \
      _Pragma("unroll")                                                             \
      for (int c2_ = 0; c2_ < 2; c2_++) {                                           \
        _Pragma("unroll")                                                           \
        for (int e_ = 0; e_ < 2; e_++) {                                            \
          unsigned int u = SRC[rt_][2*((T)&3)+c2_][e_];                             \
          TBw[(16*rt_ + 4*lg + 2*e_)*TBS + 16*c2_ + l15] = (unsigned short)(u & 0xffffu); \
          TBw[(16*rt_ + 4*lg + 2*e_ + 1)*TBS + 16*c2_ + l15] = (unsigned short)(u >> 16); \
        }                                                                           \
      }                                                                             \
    }                                                                               \
  }

  // issue phase-1 tile-0 loads (hidden under phase 0)
  load_W1(0);
  load_R(0);

  // ---------------- Phase 0: quantile-clipped weights ----------------
  if (tid < 128) {
    float a = Ab[tid];
    qa[tid] = a;
    qs[tid] = (a != 0.0f) ? a : INFINITY;
  }
  __syncthreads();
  for (int k = 2; k <= 128; k <<= 1) {
    for (int j = k >> 1; j > 0; j >>= 1) {
      if (tid < 128) {
        int ixj = tid ^ j;
        if (ixj > tid) {
          float x = qs[tid], y = qs[ixj];
          bool up = ((tid & k) == 0);
          if (up ? (x > y) : (x < y)) { qs[tid] = y; qs[ixj] = x; }
        }
      }
      __syncthreads();
    }
  }
  if (tid < 64) {
    int c = ((qa[lane] != 0.0f) ? 1 : 0) + ((qa[lane + 64] != 0.0f) ? 1 : 0);
#pragma unroll
    for (int m = 1; m < 64; m <<= 1) c += __shfl_xor(c, m, 64);
    if (lane == 0) {
      int nnz = c;
      float low = 0.0f, high = 0.0f;
      if (nnz > 0) {
        float pos = 0.1f * (float)(nnz - 1);
        int lo = (int)floorf(pos), hi = (int)ceilf(pos);
        float frac = pos - floorf(pos);
        low = qs[lo] * (1.0f - frac) + qs[hi] * frac;
        pos = 0.9f * (float)(nnz - 1);
        lo = (int)floorf(pos); hi = (int)ceilf(pos);
        frac = pos - floorf(pos);
        high = qs[lo] * (1.0f - frac) + qs[hi] * frac;
      }
      scal[0] = low; scal[1] = high;
    }
  }
  __syncthreads();
  if (tid < 128) {
    float a = qa[tid];
    qs[tid] = (a != 0.0f) ? fminf(fmaxf(a, scal[0]), scal[1]) : 0.0f;
  }
  __syncthreads();
  if (tid < 64) {
    float s = qs[lane] + qs[lane + 64];
    s = wred_sum(s);
    if (lane == 0) scal[2] = s;
  }
  __syncthreads();
  if (tid < 128) wq[tid] = qs[tid] / scal[2];

  // ---------------- Phase 1: S = W · R^T  (wave: rows 32wm..+32, cols 128wn..+128) ----------------
  f32x4 acc[16];
#pragma unroll
  for (int i = 0; i < 16; i++) acc[i] = (f32x4){0.f, 0.f, 0.f, 0.f};

  stage_R(0);
  load_R(32);
  __syncthreads();   // buf0 ready (also covers wq writes)

#pragma unroll 2
  for (int t = 0; t < 8; t++) {
    const int p = t & 1;
    half8 ah[2], al[2];
    cvtW2(ah, al);
    if (t < 7) {
      stage_R(p ^ 1);
      load_W1((t + 1) * 32);
      if (t < 6) load_R((t + 2) * 32);
    }
    unsigned short* B = SBUF(p);
#pragma unroll
    for (int ct = 0; ct < 8; ct++) {
      half8 bh = *(const half8*)(B + (128*wn + 16*ct + l15) * TS + 8*lg);
      acc[ct]     = MFMA16(ah[0], bh, acc[ct]);
      acc[ct]     = MFMA16(al[0], bh, acc[ct]);
      acc[8 + ct] = MFMA16(ah[1], bh, acc[8 + ct]);
      acc[8 + ct] = MFMA16(al[1], bh, acc[8 + ct]);
    }
    __syncthreads();
  }

  // ---------------- Phase 2: softmax (rows split across wn pair) ----------------
  load_RT(0);   // prefetch ph3 tile 0
  float fsc[2][4];
#pragma unroll
  for (int rt = 0; rt < 2; rt++)
#pragma unroll
  for (int reg = 0; reg < 4; reg++) {
    float mx = acc[rt*8][reg];
#pragma unroll
    for (int ct = 1; ct < 8; ct++) mx = fmaxf(mx, acc[rt*8+ct][reg]);
    mx = grp16_max(mx);
    float s = 0.f;
#pragma unroll
    for (int ct = 0; ct < 8; ct++) {
      float e = __expf((acc[rt*8+ct][reg] - mx) * 10.0f);
      acc[rt*8+ct][reg] = e;
      s += e;
    }
    s = grp16_sum(s);
    int row = 32*wm + 16*rt + 4*lg + reg;
    if (l15 == 0) { SMX[wn*128 + row] = mx; SSM[wn*128 + row] = s; }
    fsc[rt][reg] = mx;
  }
  __syncthreads();
#pragma unroll
  for (int rt = 0; rt < 2; rt++)
#pragma unroll
  for (int reg = 0; reg < 4; reg++) {
    int row = 32*wm + 16*rt + 4*lg + reg;
    float m0 = SMX[row], m1 = SMX[128 + row];
    float s0 = SSM[row], s1 = SSM[128 + row];
    float mx = fmaxf(m0, m1);
    float sum = s0 * __expf((m0 - mx) * 10.0f) + s1 * __expf((m1 - mx) * 10.0f);
    fsc[rt][reg] = __expf((fsc[rt][reg] - mx) * 10.0f) / sum;
  }
  unsigned int p16u[2][8][2];
#pragma unroll
  for (int rt = 0; rt < 2; rt++)
#pragma unroll
  for (int ct = 0; ct < 8; ct++) {
    p16u[rt][ct][0] = pkh(acc[rt*8+ct][0] * fsc[rt][0], acc[rt*8+ct][1] * fsc[rt][1]);
    p16u[rt][ct][1] = pkh(acc[rt*8+ct][2] * fsc[rt][2], acc[rt*8+ct][3] * fsc[rt][3]);
  }

  // ---------------- Phase 3: out = P · R  (A via cross-wave TB, B = R^T) ----------------
#pragma unroll
  for (int i = 0; i < 16; i++) acc[i] = (f32x4){0.f, 0.f, 0.f, 0.f};

  stage_RT(0);
  load_RT(32);
  TB_WRITE(p16u, 0, 0);
  __syncthreads();

#pragma unroll
  for (int t = 0; t < 8; t++) {
    const int p = t & 1;
    unsigned short* TBr = TBG(p);
    half8 pa0 = *(const half8*)(TBr + l15 * TBS + 8*lg);
    half8 pa1 = *(const half8*)(TBr + (16 + l15) * TBS + 8*lg);
    if (t < 7) {
      stage_RT(p ^ 1);
      if (t < 6) load_RT((t + 2) * 32);
      TB_WRITE(p16u, t + 1, p ^ 1);
    }
    unsigned short* B = SBUF(p);
#pragma unroll
    for (int ct = 0; ct < 8; ct++) {
      half8 bh = *(const half8*)(B + (128*wn + 16*ct + l15) * TS + 8*lg);
      acc[ct]     = MFMA16(pa0, bh, acc[ct]);
      acc[8 + ct] = MFMA16(pa1, bh, acc[8 + ct]);
    }
    __syncthreads();
  }

  // ---------------- normalize out rows (cross-wave ssq) ----------------
  load_W4(0);
#pragma unroll
  for (int rt = 0; rt < 2; rt++)
#pragma unroll
  for (int reg = 0; reg < 4; reg++) {
    float ss = 0.f;
#pragma unroll
    for (int ct = 0; ct < 8; ct++) { float v = acc[rt*8+ct][reg]; ss += v * v; }
    ss = grp16_sum(ss);
    int row = 32*wm + 16*rt + 4*lg + reg;
    if (l15 == 0) NSQ[wn*128 + row] = ss;
  }
  __syncthreads();
  float nin[2][4];
#pragma unroll
  for (int rt = 0; rt < 2; rt++)
#pragma unroll
  for (int reg = 0; reg < 4; reg++) {
    int row = 32*wm + 16*rt + 4*lg + reg;
    float ss = NSQ[row] + NSQ[128 + row];
    nin[rt][reg] = 1.0f / fmaxf(sqrtf(ss), 1e-12f);
  }
  unsigned int o16u[2][8][2];
#pragma unroll
  for (int rt = 0; rt < 2; rt++)
#pragma unroll
  for (int ct = 0; ct < 8; ct++) {
    o16u[rt][ct][0] = pkh(acc[rt*8+ct][0] * nin[rt][0], acc[rt*8+ct][1] * nin[rt][1]);
    o16u[rt][ct][1] = pkh(acc[rt*8+ct][2] * nin[rt][2], acc[rt*8+ct][3] * nin[rt][3]);
  }

  // ---------------- Phase 4: D[m][n] = out[m]·w[n]  (x10 in phase 5) ----------------
#pragma unroll
  for (int i = 0; i < 8; i++) acc[i] = (f32x4){0.f, 0.f, 0.f, 0.f};

  stage_W4(0);
  load_W4(32);
  TB_WRITE(o16u, 0, 0);
  __syncthreads();

#pragma unroll
  for (int t = 0; t < 8; t++) {
    const int p = t & 1;
    unsigned short* TBr = TBG(p);
    half8 oa0 = *(const half8*)(TBr + l15 * TBS + 8*lg);
    half8 oa1 = *(const half8*)(TBr + (16 + l15) * TBS + 8*lg);
    if (t < 7) {
      stage_W4(p ^ 1);
      if (t < 6) load_W4((t + 2) * 32);
      TB_WRITE(o16u, t + 1, p ^ 1);
    }
    unsigned short* B = SBUF(p);
#pragma unroll
    for (int ct = 0; ct < 4; ct++) {
      half8 bh = *(const half8*)(B + (64*wn + 16*ct + l15) * TS + 8*lg);
      acc[ct]     = MFMA16(oa0, bh, acc[ct]);
      acc[4 + ct] = MFMA16(oa1, bh, acc[4 + ct]);
    }
    __syncthreads();
  }
  // staging + TB dead -> PMX/PSM reuse

  // ---------------- Phase 5: lse + diag + weighted loss ----------------
  // acc[rt*4+ct][reg]: D[m][n], m = 32wm+16rt+4lg+reg, n = 64wn+16ct+l15
  // row-lse partials (over this wave's 64 cols)
#pragma unroll
  for (int rt = 0; rt < 2; rt++)
#pragma unroll
  for (int reg = 0; reg < 4; reg++) {
    float mx = acc[rt*4][reg];
#pragma unroll
    for (int ct = 1; ct < 4; ct++) mx = fmaxf(mx, acc[rt*4+ct][reg]);
    mx = grp16_max(mx);
    float s = 0.f;
#pragma unroll
    for (int ct = 0; ct < 4; ct++) s += __expf((acc[rt*4+ct][reg] - mx) * 10.0f);
    s = grp16_sum(s);
    int row = 32*wm + 16*rt + 4*lg + reg;
    if (l15 == 0) { SMX[wn*128 + row] = 10.0f * mx; SSM[wn*128 + row] = s; }
  }
  // diag
  if (wn == (wm >> 1)) {
#pragma unroll
    for (int rt = 0; rt < 2; rt++) {
      const int ctd = ((wm & 1) << 1) + rt;
#pragma unroll
      for (int reg = 0; reg < 4; reg++)
        if (l15 == 4*lg + reg) dgA[32*wm + 16*rt + 4*lg + reg] = 10.0f * acc[rt*4+ctd][reg];
    }
  }
  // col-lse partials (over this wave's 32 rows)
#pragma unroll
  for (int ct = 0; ct < 4; ct++) {
    float m4 = acc[ct][0];
#pragma unroll
    for (int reg = 1; reg < 4; reg++) m4 = fmaxf(m4, acc[ct][reg]);
#pragma unroll
    for (int reg = 0; reg < 4; reg++) m4 = fmaxf(m4, acc[4+ct][reg]);
    m4 = fmaxf(m4, __shfl_xor(m4, 16, 64));
    m4 = fmaxf(m4, __shfl_xor(m4, 32, 64));
    float s4 = 0.f;
#pragma unroll
    for (int reg = 0; reg < 4; reg++)
      s4 += __expf((acc[ct][reg] - m4) * 10.0f) + __expf((acc[4+ct][reg] - m4) * 10.0f);
    s4 += __shfl_xor(s4, 16, 64);
    s4 += __shfl_xor(s4, 32, 64);
    if (lg == 0) {
      PMX[wm*128 + 64*wn + 16*ct + l15] = 10.0f * m4;
      PSM[wm*128 + 64*wn + 16*ct + l15] = s4;
    }
  }
  __syncthreads();
  if (tid < 128) {
    float M = PMX[tid];
#pragma unroll
    for (int w = 1; w < 4; w++) M = fmaxf(M, PMX[w*128 + tid]);
    float s = 0.f;
#pragma unroll
    for (int w = 0; w < 4; w++) s += PSM[w*128 + tid] * __expf(PMX[w*128 + tid] - M);
    L1[tid] = M + __logf(s);
    float m0 = SMX[tid], m1 = SMX[128 + tid];
    float mx = fmaxf(m0, m1);
    float z = SSM[tid] * __expf(m0 - mx) + SSM[128 + tid] * __expf(m1 - mx);
    L2[tid] = mx + __logf(z);
  }
  __syncthreads();

  if (tid < 64) {
    float t = 0.0f;
#pragma unroll
    for (int q = 0; q < 2; q++) {
      int k = lane + 64 * q;
      t += wq[k] * (L1[k] + L2[k] - 2.0f * dgA[k]);
    }
    t = wred_sum(t);
    if (lane == 0) partial[b] = t;
  }
}

__global__ void reduce_partials(const float* __restrict__ p, float* __restrict__ out) {
  __shared__ float accw[4];
  int tid = threadIdx.x;
  float t = p[tid] + p[tid + 256];
  t = wred_sum(t);
  if ((tid & 63) == 0) accw[tid >> 6] = t;
  __syncthreads();
  if (tid == 0) out[0] = (accw[0] + accw[1] + accw[2] + accw[3]) * (1.0f / 1024.0f);
}

extern "C" void kernel_launch(void* const* d_in, const int* in_sizes, int n_in,
                              void* d_out, int out_size, void* d_ws, size_t ws_size,
                              hipStream_t stream) {
  const float* region = (const float*)d_in[1];
  const float* word   = (const float*)d_in[3];
  const float* wattn  = (const float*)d_in[4];
  float* out = (float*)d_out;
  float* partial = (float*)d_ws;   // 512 floats

  hipFuncSetAttribute((const void*)wra_fused,
                      hipFuncAttributeMaxDynamicSharedMemorySize, LDS_BYTES);
  hipLaunchKernelGGL(wra_fused, dim3(BZ), dim3(512), LDS_BYTES, stream,
                     region, word, wattn, partial);
  hipLaunchKernelGGL(reduce_partials, dim3(1), dim3(256), 0, stream, partial, out);
}

// Round 9
// 71.487 us; speedup vs baseline: 5.4659x; 5.4659x over previous
//
#include <hip/hip_runtime.h>
#include <math.h>

#define BZ 512
#define NW 128
#define NR 256
#define DD 256

typedef _Float16 half8 __attribute__((ext_vector_type(8)));
typedef __fp16 fp16x2 __attribute__((ext_vector_type(2)));
typedef __attribute__((ext_vector_type(4))) float f32x4;

#define MFMA16(a, b, c) __builtin_amdgcn_mfma_f32_16x16x32_f16(a, b, c, 0, 0, 0)

// ---- LDS layout (bytes) ----
constexpr int TS      = 40;       // staged tile row stride (u16 units), 80 B rows
constexpr int BUFB    = 20480;    // one staging buffer
constexpr int TB_OFF  = 40960;    // per-wave transpose buffers: 8 waves x 2 x 1280 B
constexpr int TBS     = 40;       // TB row stride (u16)
constexpr int MISC_OFF = 61440;
constexpr int LDS_BYTES = MISC_OFF + 2048;   // 63488

union PK2 { fp16x2 h; unsigned int u; };
__device__ __forceinline__ unsigned int pkh(float a, float b) {
  PK2 c; c.h = __builtin_amdgcn_cvt_pkrtz(a, b);
  return c.u;
}
union U8H { unsigned int u[4]; half8 v; };

__device__ __forceinline__ float wred_sum(float v) {
#pragma unroll
  for (int m = 1; m < 64; m <<= 1) v += __shfl_xor(v, m, 64);
  return v;
}
__device__ __forceinline__ float grp16_max(float v) {
#pragma unroll
  for (int m = 1; m < 16; m <<= 1) v = fmaxf(v, __shfl_xor(v, m, 64));
  return v;
}
__device__ __forceinline__ float grp16_sum(float v) {
#pragma unroll
  for (int m = 1; m < 16; m <<= 1) v += __shfl_xor(v, m, 64);
  return v;
}

__global__ __launch_bounds__(512, 4) void wra_fused(
    const float* __restrict__ region, const float* __restrict__ word,
    const float* __restrict__ wattn, float* __restrict__ partial)
{
  extern __shared__ char smem[];
  float* misc = (float*)(smem + MISC_OFF);
  float* PMX  = (float*)smem;              // phase-5 only (staging dead by then)
  float* PSM  = (float*)(smem + 4096);

  const int b    = blockIdx.x;
  const int tid  = threadIdx.x;
  const int lane = tid & 63;
  const int wv   = tid >> 6;   // 0..7
  const int l15  = lane & 15;
  const int lg   = lane >> 4;  // 0..3

  const float* Rb = region + (size_t)b * NR * DD;
  const float* Wb = word   + (size_t)b * NW * DD;
  const float* Ab = wattn  + (size_t)b * NW;

  float* wq   = misc;        // [128]
  float* L1   = misc + 128;  // [128]
  float* L2   = misc + 256;  // [128]
  float* dgA  = misc + 384;  // [128]

  unsigned short* TBb = (unsigned short*)(smem + TB_OFF) + wv * 1280;  // 2 x 640 u16

  const int arow = 16 * wv + l15;
  const int koff = lg * 8;

  // staging thread maps
  const int r_row = tid >> 1;          // ph1 R: 0..255
  const int r_db  = (tid & 1) * 16;
  const int rt_d  = tid & 255;         // ph3 RT
  const int rt_rc = tid >> 8;          // 0/1
  const int w4row = tid >> 2;          // ph4 W: 0..127
  const int w4db  = (tid & 3) * 8;

  float rx[16], wx1[8], rx3[16], wx4[8];

  auto SBUF = [&](int p) { return (unsigned short*)(smem + p * BUFB); };

  auto load_R = [&](int d0) {
    const float* src = Rb + r_row * DD + d0 + r_db;
#pragma unroll
    for (int q = 0; q < 4; q++) *(float4*)&rx[4*q] = *(const float4*)(src + 4*q);
  };
  auto stage_R = [&](int p) {
    U8H h0, h1;
#pragma unroll
    for (int j = 0; j < 4; j++) h0.u[j] = pkh(rx[2*j],   rx[2*j+1]);
#pragma unroll
    for (int j = 0; j < 4; j++) h1.u[j] = pkh(rx[8+2*j], rx[9+2*j]);
    *(half8*)(SBUF(p) + r_row * TS + r_db)     = h0.v;
    *(half8*)(SBUF(p) + r_row * TS + r_db + 8) = h1.v;
  };
  auto load_W1 = [&](int d0) {
    const float* src = Wb + arow * DD + d0 + koff;
    *(float4*)&wx1[0] = *(const float4*)(src);
    *(float4*)&wx1[4] = *(const float4*)(src + 4);
  };
  auto load_RT = [&](int r0) {
#pragma unroll
    for (int g = 0; g < 2; g++) {
      const float* src = Rb + (size_t)(r0 + (rt_rc + 2*g) * 8) * DD + rt_d;
#pragma unroll
      for (int i = 0; i < 8; i++) rx3[8*g + i] = src[i * DD];
    }
  };
  auto stage_RT = [&](int p) {
    U8H h0, h1;
#pragma unroll
    for (int j = 0; j < 4; j++) h0.u[j] = pkh(rx3[2*j],   rx3[2*j+1]);
#pragma unroll
    for (int j = 0; j < 4; j++) h1.u[j] = pkh(rx3[8+2*j], rx3[9+2*j]);
    *(half8*)(SBUF(p) + rt_d * TS + rt_rc * 8)       = h0.v;
    *(half8*)(SBUF(p) + rt_d * TS + (rt_rc + 2) * 8) = h1.v;
  };
  auto load_W4 = [&](int d0) {
    const float* src = Wb + w4row * DD + d0 + w4db;
    *(float4*)&wx4[0] = *(const float4*)(src);
    *(float4*)&wx4[4] = *(const float4*)(src + 4);
  };
  auto stage_W4 = [&](int p) {
    U8H h;
#pragma unroll
    for (int j = 0; j < 4; j++) h.u[j] = pkh(wx4[2*j], wx4[2*j+1]);
    *(half8*)(SBUF(p) + w4row * TS + w4db) = h.v;
  };

  // W hi/lo fp16 split (W represented to ~2^-22): a_h + a_l
  auto cvtW = [&](half8& ah, half8& al) {
    U8H H, L;
#pragma unroll
    for (int j = 0; j < 4; j++) H.u[j] = pkh(wx1[2*j], wx1[2*j+1]);
#pragma unroll
    for (int j = 0; j < 4; j++) {
      float la = wx1[2*j]   - (float)H.v[2*j];
      float lb = wx1[2*j+1] - (float)H.v[2*j+1];
      L.u[j] = pkh(la, lb);
    }
    ah = H.v; al = L.v;
  };

  // issue phase-1 tile-0 loads (hidden under phase 0)
  load_W1(0);
  load_R(0);

  // ---------------- Phase 0: quantile-clipped weights (wave 0 only, barrier-free) ----------------
  // 128-element bitonic sort held as 2 regs/lane (i0 = lane, i1 = lane+64),
  // all compare-exchanges via wave-synchronous shfl; no __syncthreads needed.
  if (wv == 0) {
    float a0 = Ab[lane], a1 = Ab[lane + 64];
    float v0 = (a0 != 0.0f) ? a0 : INFINITY;
    float v1 = (a1 != 0.0f) ? a1 : INFINITY;
    for (int k = 2; k <= 128; k <<= 1) {
      for (int j = k >> 1; j > 0; j >>= 1) {
        if (j == 64) {
          float mn = fminf(v0, v1), mxv = fmaxf(v0, v1);
          v0 = mn; v1 = mxv;        // k==128: ascending, i0 is low side
        } else {
          float y0 = __shfl_xor(v0, j, 64);
          float y1 = __shfl_xor(v1, j, 64);
          bool lo  = (lane & j) == 0;
          bool up0 = ((lane & k) == 0);
          bool up1 = (((lane + 64) & k) == 0);
          v0 = (lo == up0) ? fminf(v0, y0) : fmaxf(v0, y0);
          v1 = (lo == up1) ? fminf(v1, y1) : fmaxf(v1, y1);
        }
      }
    }
    int c = ((a0 != 0.0f) ? 1 : 0) + ((a1 != 0.0f) ? 1 : 0);
#pragma unroll
    for (int m = 1; m < 64; m <<= 1) c += __shfl_xor(c, m, 64);
    const int nnz = c;
    float low = 0.0f, high = 0.0f;
    if (nnz > 0) {
      float pos = 0.1f * (float)(nnz - 1);
      int lo_i = min(max((int)floorf(pos), 0), 127);
      int hi_i = min(max((int)ceilf(pos), 0), 127);
      float frac = pos - floorf(pos);
      float slo = (lo_i < 64) ? __shfl(v0, lo_i, 64) : __shfl(v1, lo_i - 64, 64);
      float shi = (hi_i < 64) ? __shfl(v0, hi_i, 64) : __shfl(v1, hi_i - 64, 64);
      low = slo * (1.0f - frac) + shi * frac;
      pos = 0.9f * (float)(nnz - 1);
      lo_i = min(max((int)floorf(pos), 0), 127);
      hi_i = min(max((int)ceilf(pos), 0), 127);
      frac = pos - floorf(pos);
      slo = (lo_i < 64) ? __shfl(v0, lo_i, 64) : __shfl(v1, lo_i - 64, 64);
      shi = (hi_i < 64) ? __shfl(v0, hi_i, 64) : __shfl(v1, hi_i - 64, 64);
      high = slo * (1.0f - frac) + shi * frac;
    }
    float c0 = (a0 != 0.0f) ? fminf(fmaxf(a0, low), high) : 0.0f;
    float c1 = (a1 != 0.0f) ? fminf(fmaxf(a1, low), high) : 0.0f;
    float ssum = wred_sum(c0 + c1);
    wq[lane]      = c0 / ssum;
    wq[lane + 64] = c1 / ssum;
  }

  // ---------------- Phase 1: S = W · R^T (fp16: Wh·Rh + Wl·Rh) ----------------
  f32x4 acc[16];
#pragma unroll
  for (int i = 0; i < 16; i++) acc[i] = (f32x4){0.f, 0.f, 0.f, 0.f};

  stage_R(0);
  load_R(32);
  __syncthreads();   // buf0 ready (also covers wq writes by wave 0)

#pragma unroll 2
  for (int t = 0; t < 8; t++) {
    const int p = t & 1;
    half8 a_h, a_l;
    cvtW(a_h, a_l);
    if (t < 7) {
      stage_R(p ^ 1);
      load_W1((t + 1) * 32);
      if (t < 6) load_R((t + 2) * 32);
    }
    unsigned short* B = SBUF(p);
#pragma unroll
    for (int ct = 0; ct < 16; ct++) {
      half8 b_h = *(const half8*)(B + (16 * ct + l15) * TS + koff);
      acc[ct] = MFMA16(a_h, b_h, acc[ct]);
      acc[ct] = MFMA16(a_l, b_h, acc[ct]);
    }
    __syncthreads();
  }

  // ---------------- Phase 2: softmax in registers -> packed fp16 P ----------------
  load_RT(0);   // prefetch phase-3 tile 0 under softmax
  unsigned int p16u[16][2];
#pragma unroll
  for (int reg = 0; reg < 4; reg++) {
    float mx = acc[0][reg];
#pragma unroll
    for (int ct = 1; ct < 16; ct++) mx = fmaxf(mx, acc[ct][reg]);
    mx = grp16_max(mx);
    float s = 0.f;
#pragma unroll
    for (int ct = 0; ct < 16; ct++) {
      float p = __expf((acc[ct][reg] - mx) * 10.0f);
      acc[ct][reg] = p;
      s += p;
    }
    s = grp16_sum(s);
    float inv = 1.0f / s;
#pragma unroll
    for (int ct = 0; ct < 16; ct++) acc[ct][reg] *= inv;
  }
#pragma unroll
  for (int ct = 0; ct < 16; ct++) {
    p16u[ct][0] = pkh(acc[ct][0], acc[ct][1]);
    p16u[ct][1] = pkh(acc[ct][2], acc[ct][3]);
  }

  // TB write: C-layout chunk (ct pair) -> row-major A tile for one k-tile
#define TB_WRITE(SRC, T, BF)                                              \
  {                                                                       \
    _Pragma("unroll")                                                     \
    for (int e = 0; e < 2; e++) {                                         \
      _Pragma("unroll")                                                   \
      for (int reg = 0; reg < 4; reg++) {                                 \
        unsigned int u = SRC[2 * (T) + e][reg >> 1];                      \
        unsigned short v = (reg & 1) ? (unsigned short)(u >> 16)          \
                                     : (unsigned short)(u & 0xffffu);     \
        TBb[(BF) * 640 + (4 * lg + reg) * TBS + 16 * e + l15] = v;        \
      }                                                                   \
    }                                                                     \
  }

  // ---------------- Phase 3: out = P · R (A from TB, B = R^T fp16-hi) ----------------
#pragma unroll
  for (int i = 0; i < 16; i++) acc[i] = (f32x4){0.f, 0.f, 0.f, 0.f};

  stage_RT(0);
  load_RT(32);
  TB_WRITE(p16u, 0, 0);
  __syncthreads();

#pragma unroll
  for (int t = 0; t < 8; t++) {
    const int p = t & 1;
    if (t < 7) {
      stage_RT(p ^ 1);
      if (t < 6) load_RT((t + 2) * 32);
    }
    half8 pa = *(const half8*)(TBb + p * 640 + l15 * TBS + 8 * lg);
    if (t < 7) TB_WRITE(p16u, t + 1, p ^ 1);
    unsigned short* B = SBUF(p);
#pragma unroll
    for (int ct = 0; ct < 16; ct++) {
      half8 b_h = *(const half8*)(B + (16 * ct + l15) * TS + koff);
      acc[ct] = MFMA16(pa, b_h, acc[ct]);
    }
    __syncthreads();
  }

  // normalize rows in registers, pack out to fp16
  load_W4(0);
#pragma unroll
  for (int reg = 0; reg < 4; reg++) {
    float ss = 0.f;
#pragma unroll
    for (int ct = 0; ct < 16; ct++) { float v = acc[ct][reg]; ss += v * v; }
    ss = grp16_sum(ss);
    float invn = 1.0f / fmaxf(sqrtf(ss), 1e-12f);
#pragma unroll
    for (int ct = 0; ct < 16; ct++) acc[ct][reg] *= invn;
  }
  unsigned int o16u[16][2];
#pragma unroll
  for (int ct = 0; ct < 16; ct++) {
    o16u[ct][0] = pkh(acc[ct][0], acc[ct][1]);
    o16u[ct][1] = pkh(acc[ct][2], acc[ct][3]);
  }

  // ---------------- Phase 4: D[m][n] = out[m]·w[n]  (x10 applied in phase 5) ----------------
#pragma unroll
  for (int i = 0; i < 8; i++) acc[i] = (f32x4){0.f, 0.f, 0.f, 0.f};

  stage_W4(0);
  load_W4(32);
  TB_WRITE(o16u, 0, 0);
  __syncthreads();

#pragma unroll
  for (int t = 0; t < 8; t++) {
    const int p = t & 1;
    if (t < 7) {
      stage_W4(p ^ 1);
      if (t < 6) load_W4((t + 2) * 32);
    }
    half8 oa = *(const half8*)(TBb + p * 640 + l15 * TBS + 8 * lg);
    if (t < 7) TB_WRITE(o16u, t + 1, p ^ 1);
    unsigned short* B = SBUF(p);
#pragma unroll
    for (int ct = 0; ct < 8; ct++) {
      half8 b_h = *(const half8*)(B + (16 * ct + l15) * TS + koff);
      acc[ct] = MFMA16(oa, b_h, acc[ct]);
    }
    __syncthreads();
  }
  // after this barrier, staging region is dead -> PMX/PSM reuse it

  // ---------------- Phase 5: lse + diag + weighted loss, from registers ----------------
  // acc[ct][reg]: D[m][n], m = 16wv + 4lg + reg, n = 16ct + l15; logits = 10*D
  // L2[m] = lse over n (in-lane ct + l15 group)
#pragma unroll
  for (int reg = 0; reg < 4; reg++) {
    float mx = acc[0][reg];
#pragma unroll
    for (int ct = 1; ct < 8; ct++) mx = fmaxf(mx, acc[ct][reg]);
    mx = grp16_max(mx);
    float s = 0.f;
#pragma unroll
    for (int ct = 0; ct < 8; ct++) s += __expf((acc[ct][reg] - mx) * 10.0f);
    s = grp16_sum(s);
    if (l15 == 0) L2[16 * wv + 4 * lg + reg] = 10.0f * mx + __logf(s);
  }
  // diag: n == m  ->  ct == wv, l15 == 4*lg + reg
#pragma unroll
  for (int ct = 0; ct < 8; ct++) {
    if (ct == wv) {
#pragma unroll
      for (int reg = 0; reg < 4; reg++)
        if (l15 == 4 * lg + reg) dgA[16 * wv + l15] = 10.0f * acc[ct][reg];
    }
  }
  // L1 partials: per column n, reduce over this wave's 16 m's (reg in-lane, lg via shfl)
#pragma unroll
  for (int ct = 0; ct < 8; ct++) {
    float m4 = acc[ct][0];
#pragma unroll
    for (int reg = 1; reg < 4; reg++) m4 = fmaxf(m4, acc[ct][reg]);
    m4 = fmaxf(m4, __shfl_xor(m4, 16, 64));
    m4 = fmaxf(m4, __shfl_xor(m4, 32, 64));
    float s4 = 0.f;
#pragma unroll
    for (int reg = 0; reg < 4; reg++) s4 += __expf((acc[ct][reg] - m4) * 10.0f);
    s4 += __shfl_xor(s4, 16, 64);
    s4 += __shfl_xor(s4, 32, 64);
    if (lg == 0) {
      PMX[wv * 128 + 16 * ct + l15] = 10.0f * m4;
      PSM[wv * 128 + 16 * ct + l15] = s4;
    }
  }
  __syncthreads();
  if (tid < 128) {
    float M = PMX[tid];
#pragma unroll
    for (int w = 1; w < 8; w++) M = fmaxf(M, PMX[w * 128 + tid]);
    float s = 0.f;
#pragma unroll
    for (int w = 0; w < 8; w++) s += PSM[w * 128 + tid] * __expf(PMX[w * 128 + tid] - M);
    L1[tid] = M + __logf(s);
  }
  __syncthreads();

  if (tid < 64) {
    float t = 0.0f;
#pragma unroll
    for (int q = 0; q < 2; q++) {
      int k = lane + 64 * q;
      t += wq[k] * (L1[k] + L2[k] - 2.0f * dgA[k]);
    }
    t = wred_sum(t);
    if (lane == 0) partial[b] = t;
  }
}

__global__ void reduce_partials(const float* __restrict__ p, float* __restrict__ out) {
  __shared__ float accw[4];
  int tid = threadIdx.x;
  float t = p[tid] + p[tid + 256];
  t = wred_sum(t);
  if ((tid & 63) == 0) accw[tid >> 6] = t;
  __syncthreads();
  if (tid == 0) out[0] = (accw[0] + accw[1] + accw[2] + accw[3]) * (1.0f / 1024.0f);
}

extern "C" void kernel_launch(void* const* d_in, const int* in_sizes, int n_in,
                              void* d_out, int out_size, void* d_ws, size_t ws_size,
                              hipStream_t stream) {
  const float* region = (const float*)d_in[1];
  const float* word   = (const float*)d_in[3];
  const float* wattn  = (const float*)d_in[4];
  float* out = (float*)d_out;
  float* partial = (float*)d_ws;   // 512 floats

  hipFuncSetAttribute((const void*)wra_fused,
                      hipFuncAttributeMaxDynamicSharedMemorySize, LDS_BYTES);
  hipLaunchKernelGGL(wra_fused, dim3(BZ), dim3(512), LDS_BYTES, stream,
                     region, word, wattn, partial);
  hipLaunchKernelGGL(reduce_partials, dim3(1), dim3(256), 0, stream, partial, out);
}

// Round 10
// 69.129 us; speedup vs baseline: 5.6523x; 1.0341x over previous
//
#include <hip/hip_runtime.h>
#include <math.h>

#define BZ 512
#define NW 128
#define NR 256
#define DD 256

typedef _Float16 half8 __attribute__((ext_vector_type(8)));
typedef __fp16 fp16x2 __attribute__((ext_vector_type(2)));
typedef __attribute__((ext_vector_type(4))) float f32x4;

#define MFMA16(a, b, c) __builtin_amdgcn_mfma_f32_16x16x32_f16(a, b, c, 0, 0, 0)

// ---- LDS layout (bytes) ----
constexpr int TS      = 40;       // staged tile row stride (u16 units), 80 B rows
constexpr int BUFB    = 20480;    // one staging buffer
constexpr int TB_OFF  = 40960;    // per-wave transpose buffers: 8 waves x 2 x 1280 B
constexpr int TBS     = 40;       // TB row stride (u16)
constexpr int MISC_OFF = 61440;
constexpr int LDS_BYTES = MISC_OFF + 2048;   // 63488

union PK2 { fp16x2 h; unsigned int u; };
__device__ __forceinline__ unsigned int pkh(float a, float b) {
  PK2 c; c.h = __builtin_amdgcn_cvt_pkrtz(a, b);
  return c.u;
}
union U8H { unsigned int u[4]; half8 v; };

// Barrier that drains ONLY this wave's LDS ops (lgkmcnt), leaving global
// prefetch loads in flight across the barrier (T4). All cross-wave deps in
// this kernel flow through LDS, so this is sufficient. sched_barrier pins
// the schedule so later ds_reads can't hoist above the s_barrier (rule #18).
__device__ __forceinline__ void bar_lds() {
  asm volatile("s_waitcnt lgkmcnt(0)" ::: "memory");
  __builtin_amdgcn_s_barrier();
  __builtin_amdgcn_sched_barrier(0);
}

__device__ __forceinline__ float wred_sum(float v) {
#pragma unroll
  for (int m = 1; m < 64; m <<= 1) v += __shfl_xor(v, m, 64);
  return v;
}
__device__ __forceinline__ float grp16_max(float v) {
#pragma unroll
  for (int m = 1; m < 16; m <<= 1) v = fmaxf(v, __shfl_xor(v, m, 64));
  return v;
}
__device__ __forceinline__ float grp16_sum(float v) {
#pragma unroll
  for (int m = 1; m < 16; m <<= 1) v += __shfl_xor(v, m, 64);
  return v;
}

__global__ __launch_bounds__(512, 4) void wra_fused(
    const float* __restrict__ region, const float* __restrict__ word,
    const float* __restrict__ wattn, float* __restrict__ partial)
{
  extern __shared__ char smem[];
  float* misc = (float*)(smem + MISC_OFF);
  float* PMX  = (float*)smem;              // phase-5 only (staging dead by then)
  float* PSM  = (float*)(smem + 4096);

  const int b    = blockIdx.x;
  const int tid  = threadIdx.x;
  const int lane = tid & 63;
  const int wv   = tid >> 6;   // 0..7
  const int l15  = lane & 15;
  const int lg   = lane >> 4;  // 0..3

  const float* Rb = region + (size_t)b * NR * DD;
  const float* Wb = word   + (size_t)b * NW * DD;
  const float* Ab = wattn  + (size_t)b * NW;

  float* wq   = misc;        // [128]
  float* L1   = misc + 128;  // [128]
  float* L2   = misc + 256;  // [128]
  float* dgA  = misc + 384;  // [128]

  unsigned short* TBb = (unsigned short*)(smem + TB_OFF) + wv * 1280;  // 2 x 640 u16

  const int arow = 16 * wv + l15;
  const int koff = lg * 8;

  // staging thread maps
  const int r_row = tid >> 1;          // ph1 R: 0..255
  const int r_db  = (tid & 1) * 16;
  const int rt_d  = tid & 255;         // ph3 RT
  const int rt_rc = tid >> 8;          // 0/1
  const int w4row = tid >> 2;          // ph4 W: 0..127
  const int w4db  = (tid & 3) * 8;

  float rx[16], wx1[8], rx3[16], wx4[8];

  auto SBUF = [&](int p) { return (unsigned short*)(smem + p * BUFB); };

  auto load_R = [&](int d0) {
    const float* src = Rb + r_row * DD + d0 + r_db;
#pragma unroll
    for (int q = 0; q < 4; q++) *(float4*)&rx[4*q] = *(const float4*)(src + 4*q);
  };
  auto stage_R = [&](int p) {
    U8H h0, h1;
#pragma unroll
    for (int j = 0; j < 4; j++) h0.u[j] = pkh(rx[2*j],   rx[2*j+1]);
#pragma unroll
    for (int j = 0; j < 4; j++) h1.u[j] = pkh(rx[8+2*j], rx[9+2*j]);
    *(half8*)(SBUF(p) + r_row * TS + r_db)     = h0.v;
    *(half8*)(SBUF(p) + r_row * TS + r_db + 8) = h1.v;
  };
  auto load_W1 = [&](int d0) {
    const float* src = Wb + arow * DD + d0 + koff;
    *(float4*)&wx1[0] = *(const float4*)(src);
    *(float4*)&wx1[4] = *(const float4*)(src + 4);
  };
  auto load_RT = [&](int r0) {
#pragma unroll
    for (int g = 0; g < 2; g++) {
      const float* src = Rb + (size_t)(r0 + (rt_rc + 2*g) * 8) * DD + rt_d;
#pragma unroll
      for (int i = 0; i < 8; i++) rx3[8*g + i] = src[i * DD];
    }
  };
  auto stage_RT = [&](int p) {
    U8H h0, h1;
#pragma unroll
    for (int j = 0; j < 4; j++) h0.u[j] = pkh(rx3[2*j],   rx3[2*j+1]);
#pragma unroll
    for (int j = 0; j < 4; j++) h1.u[j] = pkh(rx3[8+2*j], rx3[9+2*j]);
    *(half8*)(SBUF(p) + rt_d * TS + rt_rc * 8)       = h0.v;
    *(half8*)(SBUF(p) + rt_d * TS + (rt_rc + 2) * 8) = h1.v;
  };
  auto load_W4 = [&](int d0) {
    const float* src = Wb + w4row * DD + d0 + w4db;
    *(float4*)&wx4[0] = *(const float4*)(src);
    *(float4*)&wx4[4] = *(const float4*)(src + 4);
  };
  auto stage_W4 = [&](int p) {
    U8H h;
#pragma unroll
    for (int j = 0; j < 4; j++) h.u[j] = pkh(wx4[2*j], wx4[2*j+1]);
    *(half8*)(SBUF(p) + w4row * TS + w4db) = h.v;
  };

  // W hi/lo fp16 split (W represented to ~2^-22): a_h + a_l
  auto cvtW = [&](half8& ah, half8& al) {
    U8H H, L;
#pragma unroll
    for (int j = 0; j < 4; j++) H.u[j] = pkh(wx1[2*j], wx1[2*j+1]);
#pragma unroll
    for (int j = 0; j < 4; j++) {
      float la = wx1[2*j]   - (float)H.v[2*j];
      float lb = wx1[2*j+1] - (float)H.v[2*j+1];
      L.u[j] = pkh(la, lb);
    }
    ah = H.v; al = L.v;
  };

  // issue phase-1 tile-0 loads (hidden under phase 0)
  load_W1(0);
  load_R(0);

  // ---------------- Phase 0: quantile-clipped weights (wave 0 only, barrier-free) ----------------
  if (wv == 0) {
    float a0 = Ab[lane], a1 = Ab[lane + 64];
    float v0 = (a0 != 0.0f) ? a0 : INFINITY;
    float v1 = (a1 != 0.0f) ? a1 : INFINITY;
    for (int k = 2; k <= 128; k <<= 1) {
      for (int j = k >> 1; j > 0; j >>= 1) {
        if (j == 64) {
          float mn = fminf(v0, v1), mxv = fmaxf(v0, v1);
          v0 = mn; v1 = mxv;        // k==128: ascending, i0 is low side
        } else {
          float y0 = __shfl_xor(v0, j, 64);
          float y1 = __shfl_xor(v1, j, 64);
          bool lo  = (lane & j) == 0;
          bool up0 = ((lane & k) == 0);
          bool up1 = (((lane + 64) & k) == 0);
          v0 = (lo == up0) ? fminf(v0, y0) : fmaxf(v0, y0);
          v1 = (lo == up1) ? fminf(v1, y1) : fmaxf(v1, y1);
        }
      }
    }
    int c = ((a0 != 0.0f) ? 1 : 0) + ((a1 != 0.0f) ? 1 : 0);
#pragma unroll
    for (int m = 1; m < 64; m <<= 1) c += __shfl_xor(c, m, 64);
    const int nnz = c;
    float low = 0.0f, high = 0.0f;
    if (nnz > 0) {
      float pos = 0.1f * (float)(nnz - 1);
      int lo_i = min(max((int)floorf(pos), 0), 127);
      int hi_i = min(max((int)ceilf(pos), 0), 127);
      float frac = pos - floorf(pos);
      float slo = (lo_i < 64) ? __shfl(v0, lo_i, 64) : __shfl(v1, lo_i - 64, 64);
      float shi = (hi_i < 64) ? __shfl(v0, hi_i, 64) : __shfl(v1, hi_i - 64, 64);
      low = slo * (1.0f - frac) + shi * frac;
      pos = 0.9f * (float)(nnz - 1);
      lo_i = min(max((int)floorf(pos), 0), 127);
      hi_i = min(max((int)ceilf(pos), 0), 127);
      frac = pos - floorf(pos);
      slo = (lo_i < 64) ? __shfl(v0, lo_i, 64) : __shfl(v1, lo_i - 64, 64);
      shi = (hi_i < 64) ? __shfl(v0, hi_i, 64) : __shfl(v1, hi_i - 64, 64);
      high = slo * (1.0f - frac) + shi * frac;
    }
    float c0 = (a0 != 0.0f) ? fminf(fmaxf(a0, low), high) : 0.0f;
    float c1 = (a1 != 0.0f) ? fminf(fmaxf(a1, low), high) : 0.0f;
    float ssum = wred_sum(c0 + c1);
    wq[lane]      = c0 / ssum;
    wq[lane + 64] = c1 / ssum;
  }

  // ---------------- Phase 1: S = W · R^T (fp16: Wh·Rh + Wl·Rh) ----------------
  f32x4 acc[16];
#pragma unroll
  for (int i = 0; i < 16; i++) acc[i] = (f32x4){0.f, 0.f, 0.f, 0.f};

  stage_R(0);
  load_R(32);
  bar_lds();   // buf0 ready (also covers wq writes by wave 0)

#pragma unroll 2
  for (int t = 0; t < 8; t++) {
    const int p = t & 1;
    half8 a_h, a_l;
    cvtW(a_h, a_l);
    if (t < 7) {
      stage_R(p ^ 1);
      load_W1((t + 1) * 32);
      if (t < 6) load_R((t + 2) * 32);
    }
    unsigned short* B = SBUF(p);
#pragma unroll
    for (int ct = 0; ct < 16; ct++) {
      half8 b_h = *(const half8*)(B + (16 * ct + l15) * TS + koff);
      acc[ct] = MFMA16(a_h, b_h, acc[ct]);
      acc[ct] = MFMA16(a_l, b_h, acc[ct]);
    }
    bar_lds();
  }

  // ---------------- Phase 2: softmax in registers -> packed fp16 P ----------------
  load_RT(0);   // prefetch phase-3 tile 0 under softmax
  unsigned int p16u[16][2];
#pragma unroll
  for (int reg = 0; reg < 4; reg++) {
    float mx = acc[0][reg];
#pragma unroll
    for (int ct = 1; ct < 16; ct++) mx = fmaxf(mx, acc[ct][reg]);
    mx = grp16_max(mx);
    float s = 0.f;
#pragma unroll
    for (int ct = 0; ct < 16; ct++) {
      float p = __expf((acc[ct][reg] - mx) * 10.0f);
      acc[ct][reg] = p;
      s += p;
    }
    s = grp16_sum(s);
    float inv = 1.0f / s;
#pragma unroll
    for (int ct = 0; ct < 16; ct++) acc[ct][reg] *= inv;
  }
#pragma unroll
  for (int ct = 0; ct < 16; ct++) {
    p16u[ct][0] = pkh(acc[ct][0], acc[ct][1]);
    p16u[ct][1] = pkh(acc[ct][2], acc[ct][3]);
  }

  // TB write: C-layout chunk (ct pair) -> row-major A tile for one k-tile
#define TB_WRITE(SRC, T, BF)                                              \
  {                                                                       \
    _Pragma("unroll")                                                     \
    for (int e = 0; e < 2; e++) {                                         \
      _Pragma("unroll")                                                   \
      for (int reg = 0; reg < 4; reg++) {                                 \
        unsigned int u = SRC[2 * (T) + e][reg >> 1];                      \
        unsigned short v = (reg & 1) ? (unsigned short)(u >> 16)          \
                                     : (unsigned short)(u & 0xffffu);     \
        TBb[(BF) * 640 + (4 * lg + reg) * TBS + 16 * e + l15] = v;        \
      }                                                                   \
    }                                                                     \
  }

  // ---------------- Phase 3: out = P · R (A from TB, B = R^T fp16-hi) ----------------
#pragma unroll
  for (int i = 0; i < 16; i++) acc[i] = (f32x4){0.f, 0.f, 0.f, 0.f};

  stage_RT(0);
  load_RT(32);
  TB_WRITE(p16u, 0, 0);
  bar_lds();

#pragma unroll
  for (int t = 0; t < 8; t++) {
    const int p = t & 1;
    if (t < 7) {
      stage_RT(p ^ 1);
      if (t < 6) load_RT((t + 2) * 32);
    }
    half8 pa = *(const half8*)(TBb + p * 640 + l15 * TBS + 8 * lg);
    if (t < 7) TB_WRITE(p16u, t + 1, p ^ 1);
    unsigned short* B = SBUF(p);
#pragma unroll
    for (int ct = 0; ct < 16; ct++) {
      half8 b_h = *(const half8*)(B + (16 * ct + l15) * TS + koff);
      acc[ct] = MFMA16(pa, b_h, acc[ct]);
    }
    bar_lds();
  }

  // normalize rows in registers, pack out to fp16
  load_W4(0);
#pragma unroll
  for (int reg = 0; reg < 4; reg++) {
    float ss = 0.f;
#pragma unroll
    for (int ct = 0; ct < 16; ct++) { float v = acc[ct][reg]; ss += v * v; }
    ss = grp16_sum(ss);
    float invn = 1.0f / fmaxf(sqrtf(ss), 1e-12f);
#pragma unroll
    for (int ct = 0; ct < 16; ct++) acc[ct][reg] *= invn;
  }
  unsigned int o16u[16][2];
#pragma unroll
  for (int ct = 0; ct < 16; ct++) {
    o16u[ct][0] = pkh(acc[ct][0], acc[ct][1]);
    o16u[ct][1] = pkh(acc[ct][2], acc[ct][3]);
  }

  // ---------------- Phase 4: D[m][n] = out[m]·w[n]  (x10 applied in phase 5) ----------------
#pragma unroll
  for (int i = 0; i < 8; i++) acc[i] = (f32x4){0.f, 0.f, 0.f, 0.f};

  stage_W4(0);
  load_W4(32);
  TB_WRITE(o16u, 0, 0);
  bar_lds();

#pragma unroll
  for (int t = 0; t < 8; t++) {
    const int p = t & 1;
    if (t < 7) {
      stage_W4(p ^ 1);
      if (t < 6) load_W4((t + 2) * 32);
    }
    half8 oa = *(const half8*)(TBb + p * 640 + l15 * TBS + 8 * lg);
    if (t < 7) TB_WRITE(o16u, t + 1, p ^ 1);
    unsigned short* B = SBUF(p);
#pragma unroll
    for (int ct = 0; ct < 8; ct++) {
      half8 b_h = *(const half8*)(B + (16 * ct + l15) * TS + koff);
      acc[ct] = MFMA16(oa, b_h, acc[ct]);
    }
    bar_lds();
  }
  // after this barrier, staging region is dead -> PMX/PSM reuse it

  // ---------------- Phase 5: lse + diag + weighted loss, from registers ----------------
  // acc[ct][reg]: D[m][n], m = 16wv + 4lg + reg, n = 16ct + l15; logits = 10*D
  // L2[m] = lse over n (in-lane ct + l15 group)
#pragma unroll
  for (int reg = 0; reg < 4; reg++) {
    float mx = acc[0][reg];
#pragma unroll
    for (int ct = 1; ct < 8; ct++) mx = fmaxf(mx, acc[ct][reg]);
    mx = grp16_max(mx);
    float s = 0.f;
#pragma unroll
    for (int ct = 0; ct < 8; ct++) s += __expf((acc[ct][reg] - mx) * 10.0f);
    s = grp16_sum(s);
    if (l15 == 0) L2[16 * wv + 4 * lg + reg] = 10.0f * mx + __logf(s);
  }
  // diag: n == m  ->  ct == wv, l15 == 4*lg + reg
#pragma unroll
  for (int ct = 0; ct < 8; ct++) {
    if (ct == wv) {
#pragma unroll
      for (int reg = 0; reg < 4; reg++)
        if (l15 == 4 * lg + reg) dgA[16 * wv + l15] = 10.0f * acc[ct][reg];
    }
  }
  // L1 partials: per column n, reduce over this wave's 16 m's (reg in-lane, lg via shfl)
#pragma unroll
  for (int ct = 0; ct < 8; ct++) {
    float m4 = acc[ct][0];
#pragma unroll
    for (int reg = 1; reg < 4; reg++) m4 = fmaxf(m4, acc[ct][reg]);
    m4 = fmaxf(m4, __shfl_xor(m4, 16, 64));
    m4 = fmaxf(m4, __shfl_xor(m4, 32, 64));
    float s4 = 0.f;
#pragma unroll
    for (int reg = 0; reg < 4; reg++) s4 += __expf((acc[ct][reg] - m4) * 10.0f);
    s4 += __shfl_xor(s4, 16, 64);
    s4 += __shfl_xor(s4, 32, 64);
    if (lg == 0) {
      PMX[wv * 128 + 16 * ct + l15] = 10.0f * m4;
      PSM[wv * 128 + 16 * ct + l15] = s4;
    }
  }
  bar_lds();
  if (tid < 128) {
    float M = PMX[tid];
#pragma unroll
    for (int w = 1; w < 8; w++) M = fmaxf(M, PMX[w * 128 + tid]);
    float s = 0.f;
#pragma unroll
    for (int w = 0; w < 8; w++) s += PSM[w * 128 + tid] * __expf(PMX[w * 128 + tid] - M);
    L1[tid] = M + __logf(s);
  }
  bar_lds();

  if (tid < 64) {
    float t = 0.0f;
#pragma unroll
    for (int q = 0; q < 2; q++) {
      int k = lane + 64 * q;
      t += wq[k] * (L1[k] + L2[k] - 2.0f * dgA[k]);
    }
    t = wred_sum(t);
    if (lane == 0) partial[b] = t;
  }
}

__global__ void reduce_partials(const float* __restrict__ p, float* __restrict__ out) {
  __shared__ float accw[4];
  int tid = threadIdx.x;
  float t = p[tid] + p[tid + 256];
  t = wred_sum(t);
  if ((tid & 63) == 0) accw[tid >> 6] = t;
  __syncthreads();
  if (tid == 0) out[0] = (accw[0] + accw[1] + accw[2] + accw[3]) * (1.0f / 1024.0f);
}

extern "C" void kernel_launch(void* const* d_in, const int* in_sizes, int n_in,
                              void* d_out, int out_size, void* d_ws, size_t ws_size,
                              hipStream_t stream) {
  const float* region = (const float*)d_in[1];
  const float* word   = (const float*)d_in[3];
  const float* wattn  = (const float*)d_in[4];
  float* out = (float*)d_out;
  float* partial = (float*)d_ws;   // 512 floats

  hipFuncSetAttribute((const void*)wra_fused,
                      hipFuncAttributeMaxDynamicSharedMemorySize, LDS_BYTES);
  hipLaunchKernelGGL(wra_fused, dim3(BZ), dim3(512), LDS_BYTES, stream,
                     region, word, wattn, partial);
  hipLaunchKernelGGL(reduce_partials, dim3(1), dim3(256), 0, stream, partial, out);
}